// Round 7
// baseline (583.307 us; speedup 1.0000x reference)
//
#include <hip/hip_runtime.h>
#include <hip/hip_bf16.h>

typedef __bf16 bf16x8 __attribute__((ext_vector_type(8)));
typedef float f32x4 __attribute__((ext_vector_type(4)));
typedef float f32x2 __attribute__((ext_vector_type(2)));

#define CC 256

// strip-local swizzled offsets (per-wave 16KB strip)
// h1 area: [16 rows][512 cols] bf16, row stride 1024B
__device__ __forceinline__ int swzH(int r, int c) {
    return r * 1024 + ((c * 2) ^ ((r & 7) << 4));
}
// o area: [16 rows][256 cols] bf16 at byte 8192, row stride 512B
__device__ __forceinline__ int swzO(int r, int c) {
    return 8192 + r * 512 + ((c * 2) ^ ((r & 7) << 4));
}

// A-fragment from global fp32 row-major [.][256]: lane(q4,r16) -> row, k0..k0+8
__device__ __forceinline__ bf16x8 afrag(const float* __restrict__ src, int row, int k0) {
    f32x4 v0 = __builtin_nontemporal_load((const f32x4*)(src + (size_t)row * CC + k0));
    f32x4 v1 = __builtin_nontemporal_load((const f32x4*)(src + (size_t)row * CC + k0 + 4));
    bf16x8 a;
    a[0] = (__bf16)v0[0]; a[1] = (__bf16)v0[1]; a[2] = (__bf16)v0[2]; a[3] = (__bf16)v0[3];
    a[4] = (__bf16)v1[0]; a[5] = (__bf16)v1[1]; a[6] = (__bf16)v1[2]; a[7] = (__bf16)v1[3];
    return a;
}

// weight prep: transpose + bf16 convert. layout (bf16 elem offsets):
//   WTqp @0 [256][512] (k<256: Wq, k>=256: Wpos) | WTkp @131072 [256][512]
//   WTo1 @262144 [512][256] | WTo2 @393216 [64][512] | WTv @425984 [256][256]
//   WTout @491520 [256][256]
__global__ void prep_all(const float* __restrict__ Wq, const float* __restrict__ Wk,
                         const float* __restrict__ Wpos, const float* __restrict__ Wo1,
                         const float* __restrict__ Wo2, const float* __restrict__ Wv,
                         const float* __restrict__ Wout, __bf16* __restrict__ ws)
{
    int i = blockIdx.x * 256 + threadIdx.x;
    if (i >= 557056) return;
    float v;
    if (i < 131072) {
        int n = i >> 9, k = i & 511;
        v = (k < 256) ? Wq[k * 256 + n] : Wpos[(k - 256) * 256 + n];
    } else if (i < 262144) {
        int j = i - 131072, n = j >> 9, k = j & 511;
        v = (k < 256) ? Wk[k * 256 + n] : Wpos[(k - 256) * 256 + n];
    } else if (i < 393216) {
        int j = i - 262144, n = j >> 8, k = j & 255;
        v = Wo1[k * 512 + n];
    } else if (i < 425984) {
        int j = i - 393216, n = j >> 9, k = j & 511;
        v = Wo2[k * 64 + n];
    } else if (i < 491520) {
        int j = i - 425984, n = j >> 8, k = j & 255;
        v = Wv[k * 256 + n];
    } else {
        int j = i - 491520, n = j >> 8, k = j & 255;
        v = Wout[k * 256 + n];
    }
    ws[i] = (__bf16)v;
}

// ============ single fused kernel: barrier-free, wave-private 16-token strips ============
extern "C" __global__ void __launch_bounds__(512, 2)
fused_all(const float* __restrict__ query, const float* __restrict__ key,
          const float* __restrict__ value, const float* __restrict__ refp,
          const float* __restrict__ pose,
          const __bf16* __restrict__ ws,
          const float* __restrict__ bq, const float* __restrict__ bk,
          const float* __restrict__ bv, const float* __restrict__ bpos,
          const float* __restrict__ bo1, const float* __restrict__ bo2,
          const float* __restrict__ bout,
          float* __restrict__ out)
{
    const __bf16* WTqp = ws;
    const __bf16* WTkp = ws + 131072;
    const __bf16* WTo1 = ws + 262144;
    const __bf16* WTo2 = ws + 393216;
    const __bf16* WTv   = ws + 425984;
    const __bf16* WTout = ws + 491520;

    __shared__ __attribute__((aligned(16))) char STRIP[8 * 16384];

    const int tid = threadIdx.x;
    const int lane = tid & 63;
    const int wid = tid >> 6;         // 0..7
    const int r16 = lane & 15;
    const int q4 = lane >> 4;
    const int row0 = blockIdx.x * 128 + wid * 16;   // this wave's 16 tokens
    char* strip = STRIP + wid * 16384;

    // ---- load query A-frags once (K=256 -> 8 frags, 32 VGPR) ----
    bf16x8 qf[8];
#pragma unroll
    for (int ks = 0; ks < 8; ++ks)
        qf[ks] = afrag(query, row0 + r16, ks * 32 + q4 * 8);

    // ---- h1 = relu(query@Wo1+bo1): 8 chunks of 64 cols -> strip h1 area ----
    for (int ch = 0; ch < 8; ++ch) {
        f32x4 acc[4];
#pragma unroll
        for (int nf = 0; nf < 4; ++nf) acc[nf] = (f32x4){0.f, 0.f, 0.f, 0.f};
#pragma unroll
        for (int ks = 0; ks < 8; ++ks) {
            int k0 = ks * 32 + q4 * 8;
#pragma unroll
            for (int nf = 0; nf < 4; ++nf) {
                bf16x8 b = *(const bf16x8*)(WTo1 + (size_t)(ch * 64 + nf * 16 + r16) * 256 + k0);
                acc[nf] = __builtin_amdgcn_mfma_f32_16x16x32_bf16(qf[ks], b, acc[nf], 0, 0, 0);
            }
        }
#pragma unroll
        for (int nf = 0; nf < 4; ++nf) {
            int col = ch * 64 + nf * 16 + r16;
            float bias = bo1[col];
#pragma unroll
            for (int r = 0; r < 4; ++r)
                *(__bf16*)(strip + swzH(q4 * 4 + r, col)) =
                    (__bf16)fmaxf(acc[nf][r] + bias, 0.f);
        }
    }

    // ---- off = h1 @ Wo2 + bo2  ([16 tok][64]) ----
    f32x4 accO[4];
#pragma unroll
    for (int nf = 0; nf < 4; ++nf) accO[nf] = (f32x4){0.f, 0.f, 0.f, 0.f};
#pragma unroll
    for (int ks = 0; ks < 16; ++ks) {
        int k0 = ks * 32 + q4 * 8;
        bf16x8 a = *(const bf16x8*)(strip + swzH(r16, k0));
#pragma unroll
        for (int nf = 0; nf < 4; ++nf) {
            bf16x8 b = *(const bf16x8*)(WTo2 + (size_t)(nf * 16 + r16) * 512 + k0);
            accO[nf] = __builtin_amdgcn_mfma_f32_16x16x32_bf16(a, b, accO[nf], 0, 0, 0);
        }
    }
    // drain h1 reads before overwriting strip bytes (WAR fence), then write off fp32 [16][64] @0
    asm volatile("s_waitcnt lgkmcnt(0)" ::: "memory");
    __builtin_amdgcn_sched_barrier(0);
    float* offA = (float*)strip;
    {
#pragma unroll
        for (int nf = 0; nf < 4; ++nf) {
            int col = nf * 16 + r16;
            float b2 = bo2[col];
#pragma unroll
            for (int r = 0; r < 4; ++r)
                offA[(q4 * 4 + r) * 64 + col] = accO[nf][r] + b2;
        }
    }

    // ---- load pose/key A-frags ----
    bf16x8 pf[8], kf[8];
#pragma unroll
    for (int ks = 0; ks < 8; ++ks) {
        pf[ks] = afrag(pose, row0 + r16, ks * 32 + q4 * 8);
        kf[ks] = afrag(key, row0 + r16, ks * 32 + q4 * 8);
    }

    // ---- qk: 4 chunks of 64 cols (= 2 heads each); q,k never materialized ----
    float* qk_s = (float*)(strip + 4224);   // [16][8]
    for (int ch = 0; ch < 4; ++ch) {
        f32x4 qa[4], ka[4];
#pragma unroll
        for (int nf = 0; nf < 4; ++nf) {
            qa[nf] = (f32x4){0.f, 0.f, 0.f, 0.f};
            ka[nf] = (f32x4){0.f, 0.f, 0.f, 0.f};
        }
#pragma unroll
        for (int ks = 0; ks < 8; ++ks) {
            int k0 = ks * 32 + q4 * 8;
#pragma unroll
            for (int nf = 0; nf < 4; ++nf) {
                size_t cidx = (size_t)(ch * 64 + nf * 16 + r16) * 512 + k0;
                bf16x8 bqf = *(const bf16x8*)(WTqp + cidx);
                bf16x8 bkf = *(const bf16x8*)(WTkp + cidx);
                qa[nf] = __builtin_amdgcn_mfma_f32_16x16x32_bf16(qf[ks], bqf, qa[nf], 0, 0, 0);
                ka[nf] = __builtin_amdgcn_mfma_f32_16x16x32_bf16(kf[ks], bkf, ka[nf], 0, 0, 0);
            }
        }
#pragma unroll
        for (int ks = 0; ks < 8; ++ks) {
            int k0 = 256 + ks * 32 + q4 * 8;
#pragma unroll
            for (int nf = 0; nf < 4; ++nf) {
                size_t cidx = (size_t)(ch * 64 + nf * 16 + r16) * 512 + k0;
                bf16x8 bqf = *(const bf16x8*)(WTqp + cidx);
                bf16x8 bkf = *(const bf16x8*)(WTkp + cidx);
                qa[nf] = __builtin_amdgcn_mfma_f32_16x16x32_bf16(pf[ks], bqf, qa[nf], 0, 0, 0);
                ka[nf] = __builtin_amdgcn_mfma_f32_16x16x32_bf16(pf[ks], bkf, ka[nf], 0, 0, 0);
            }
        }
        float Bq[4], Bk[4];
#pragma unroll
        for (int nf = 0; nf < 4; ++nf) {
            int col = ch * 64 + nf * 16 + r16;
            Bq[nf] = bq[col] + bpos[col];
            Bk[nf] = bk[col] + bpos[col];
        }
#pragma unroll
        for (int r = 0; r < 4; ++r) {
            float p0 = (qa[0][r] + Bq[0]) * (ka[0][r] + Bk[0])
                     + (qa[1][r] + Bq[1]) * (ka[1][r] + Bk[1]);
            float p1 = (qa[2][r] + Bq[2]) * (ka[2][r] + Bk[2])
                     + (qa[3][r] + Bq[3]) * (ka[3][r] + Bk[3]);
#pragma unroll
            for (int m = 1; m < 16; m <<= 1) {
                p0 += __shfl_xor(p0, m);
                p1 += __shfl_xor(p1, m);
            }
            if (r16 == 0) {
                int t = q4 * 4 + r;
                qk_s[t * 8 + ch * 2] = p0;
                qk_s[t * 8 + ch * 2 + 1] = p1;
            }
        }
    }

    // ---- softmax -> wv (2 (t,h) jobs per lane, all intra-wave) ----
    float* wv_s = (float*)(strip + 4864);   // [16][8]
#pragma unroll
    for (int pi = 0; pi < 2; ++pi) {
        int j = lane + pi * 64;
        int t = j >> 3, h = j & 7;
        float qk = qk_s[t * 8 + h];
        f32x2 rp = __builtin_nontemporal_load((const f32x2*)(refp + (size_t)(row0 + t) * 2));
        float wgt[4], lg[4];
        float m = -1e30f;
#pragma unroll
        for (int kk = 0; kk < 4; ++kk) {
            float ox = offA[t * 64 + (h * 4 + kk) * 2];
            float oy = offA[t * 64 + (h * 4 + kk) * 2 + 1];
            float cx = rp[0] + ox - 0.5f, cy = rp[1] + oy - 0.5f;
            float wx = fmaxf(0.f, 1.f - fabsf(cx));
            float wy = fmaxf(0.f, 1.f - fabsf(cy));
            wgt[kk] = wx * wy;
            lg[kk] = qk * wgt[kk] * 0.17677669529663687f;  // 1/sqrt(32)
            m = fmaxf(m, lg[kk]);
        }
        float s = 0.f, sw = 0.f;
#pragma unroll
        for (int kk = 0; kk < 4; ++kk) {
            float e = __expf(lg[kk] - m);
            s += e;
            sw += e * wgt[kk];
        }
        wv_s[t * 8 + h] = sw / s;
    }

    // ---- value A-frags (reuses register budget of qf/pf/kf, now dead) ----
    bf16x8 vf[8];
#pragma unroll
    for (int ks = 0; ks < 8; ++ks)
        vf[ks] = afrag(value, row0 + r16, ks * 32 + q4 * 8);

    // ---- o = (value@Wv + bv) * wv -> strip o area ----
    asm volatile("s_waitcnt lgkmcnt(0)" ::: "memory");
    __builtin_amdgcn_sched_barrier(0);
    for (int ch = 0; ch < 4; ++ch) {
        f32x4 acc[4];
#pragma unroll
        for (int nf = 0; nf < 4; ++nf) acc[nf] = (f32x4){0.f, 0.f, 0.f, 0.f};
#pragma unroll
        for (int ks = 0; ks < 8; ++ks) {
            int k0 = ks * 32 + q4 * 8;
#pragma unroll
            for (int nf = 0; nf < 4; ++nf) {
                bf16x8 b = *(const bf16x8*)(WTv + (size_t)(ch * 64 + nf * 16 + r16) * 256 + k0);
                acc[nf] = __builtin_amdgcn_mfma_f32_16x16x32_bf16(vf[ks], b, acc[nf], 0, 0, 0);
            }
        }
#pragma unroll
        for (int nf = 0; nf < 4; ++nf) {
            int col = ch * 64 + nf * 16 + r16;
            int head = ch * 2 + (nf >> 1);
            float bias = bv[col];
#pragma unroll
            for (int r = 0; r < 4; ++r) {
                int t = q4 * 4 + r;
                float wvv = wv_s[t * 8 + head];
                *(__bf16*)(strip + swzO(t, col)) = (__bf16)((acc[nf][r] + bias) * wvv);
            }
        }
    }

    // ---- out = o @ WTout + bout -> global (NT stores) ----
    for (int ch = 0; ch < 4; ++ch) {
        f32x4 acc[4];
#pragma unroll
        for (int nf = 0; nf < 4; ++nf) acc[nf] = (f32x4){0.f, 0.f, 0.f, 0.f};
#pragma unroll
        for (int ks = 0; ks < 8; ++ks) {
            int k0 = ks * 32 + q4 * 8;
            bf16x8 a = *(const bf16x8*)(strip + swzO(r16, k0));
#pragma unroll
            for (int nf = 0; nf < 4; ++nf) {
                bf16x8 b = *(const bf16x8*)(WTout + (size_t)(ch * 64 + nf * 16 + r16) * 256 + k0);
                acc[nf] = __builtin_amdgcn_mfma_f32_16x16x32_bf16(a, b, acc[nf], 0, 0, 0);
            }
        }
#pragma unroll
        for (int nf = 0; nf < 4; ++nf) {
            int col = ch * 64 + nf * 16 + r16;
            float bias = bout[col];
#pragma unroll
            for (int r = 0; r < 4; ++r)
                __builtin_nontemporal_store(acc[nf][r] + bias,
                                            out + (size_t)(row0 + q4 * 4 + r) * CC + col);
        }
    }
}

extern "C" void kernel_launch(void* const* d_in, const int* in_sizes, int n_in,
                              void* d_out, int out_size, void* d_ws, size_t ws_size,
                              hipStream_t stream)
{
    const float* query = (const float*)d_in[0];
    const float* key   = (const float*)d_in[1];
    const float* value = (const float*)d_in[2];
    const float* refp  = (const float*)d_in[3];
    const float* pose  = (const float*)d_in[4];
    const float* Wq  = (const float*)d_in[5];  const float* bq   = (const float*)d_in[6];
    const float* Wk  = (const float*)d_in[7];  const float* bk   = (const float*)d_in[8];
    const float* Wv  = (const float*)d_in[9];  const float* bv   = (const float*)d_in[10];
    const float* Wo1 = (const float*)d_in[11]; const float* bo1  = (const float*)d_in[12];
    const float* Wo2 = (const float*)d_in[13]; const float* bo2  = (const float*)d_in[14];
    const float* Wpos= (const float*)d_in[15]; const float* bpos = (const float*)d_in[16];
    const float* Wout= (const float*)d_in[17]; const float* bout = (const float*)d_in[18];

    __bf16* ws = (__bf16*)d_ws;

    prep_all<<<2176, 256, 0, stream>>>(Wq, Wk, Wpos, Wo1, Wo2, Wv, Wout, ws);

    fused_all<<<65536 / 128, 512, 0, stream>>>(
        query, key, value, refp, pose, ws,
        bq, bk, bv, bpos, bo1, bo2, bout, (float*)d_out);
}

// Round 8
// 308.481 us; speedup vs baseline: 1.8909x; 1.8909x over previous
//
#include <hip/hip_runtime.h>
#include <hip/hip_bf16.h>

typedef __bf16 bf16x8 __attribute__((ext_vector_type(8)));
typedef float f32x4 __attribute__((ext_vector_type(4)));
typedef float f32x2 __attribute__((ext_vector_type(2)));

#define MT 32   // tokens per tile
#define CC 256

// swizzled LDS byte offset for element (r, c) of a [.][256] bf16 tile
__device__ __forceinline__ int swz(int r, int c) {
    return r * 512 + ((c * 2) ^ ((r & 7) << 4));
}

// Per-wave GEMM tile with per-block K-order rotation (de-correlates the L2 weight
// address streams of concurrently-running blocks; ROT in [0,8)).
template<int MREP, int NREP, int NKS>
__device__ __forceinline__ void mfma_tile(const __bf16* A_lds, const __bf16* __restrict__ WT,
                                          int wK, int colbase, int b_k0,
                                          f32x4 (&acc)[MREP][NREP], int r16, int q4, int rot)
{
#pragma unroll
    for (int ks = 0; ks < NKS; ++ks) {
        int kse = (ks + rot) & (NKS - 1);
        int ak = kse * 32 + q4 * 8;
        int bk = b_k0 + kse * 32 + q4 * 8;
        bf16x8 a[MREP], b[NREP];
#pragma unroll
        for (int mf = 0; mf < MREP; ++mf)
            a[mf] = *(const bf16x8*)((const char*)A_lds + swz(mf * 16 + r16, ak));
#pragma unroll
        for (int nf = 0; nf < NREP; ++nf)
            b[nf] = *(const bf16x8*)(WT + (size_t)(colbase + nf * 16 + r16) * wK + bk);
#pragma unroll
        for (int mf = 0; mf < MREP; ++mf)
#pragma unroll
            for (int nf = 0; nf < NREP; ++nf)
                acc[mf][nf] = __builtin_amdgcn_mfma_f32_16x16x32_bf16(a[mf], b[nf], acc[mf][nf], 0, 0, 0);
    }
}

__device__ __forceinline__ void zero4(f32x4 (&acc)[2][4]) {
#pragma unroll
    for (int i = 0; i < 2; ++i)
#pragma unroll
        for (int j = 0; j < 4; ++j)
            acc[i][j] = (f32x4){0.f, 0.f, 0.f, 0.f};
}

// non-temporal staging: activations are single-use streams — keep them out of L2.
__device__ __forceinline__ void stage_load(const float* __restrict__ src, int row0, int tid,
                                           f32x4 (&v)[8]) {
#pragma unroll
    for (int i = 0; i < 8; ++i) {
        int f = i * 256 + tid;
        int r = f >> 6;
        int c = (f & 63) * 4;
        v[i] = __builtin_nontemporal_load((const f32x4*)(src + (size_t)(row0 + r) * CC + c));
    }
}
__device__ __forceinline__ void stage_write(__bf16* dst, int tid, const f32x4 (&v)[8]) {
#pragma unroll
    for (int i = 0; i < 8; ++i) {
        int f = i * 256 + tid;
        int r = f >> 6;
        int c = (f & 63) * 4;
        union { __bf16 h[4]; unsigned long long u; } uu;
        uu.h[0] = (__bf16)v[i][0]; uu.h[1] = (__bf16)v[i][1];
        uu.h[2] = (__bf16)v[i][2]; uu.h[3] = (__bf16)v[i][3];
        *(unsigned long long*)((char*)dst + swz(r, c)) = uu.u;
    }
}

// weight prep: transpose + bf16 convert. layout (bf16 elem offsets):
//   WTqp @0 [256][512] (k<256: Wq, k>=256: Wpos) | WTkp @131072 [256][512]
//   WTo1 @262144 [512][256] | WTo2 @393216 [64][512] | WTv @425984 [256][256]
//   WTout @491520 [256][256]   (total 557056 bf16 = 1114112 B)
__global__ void prep_all(const float* __restrict__ Wq, const float* __restrict__ Wk,
                         const float* __restrict__ Wpos, const float* __restrict__ Wo1,
                         const float* __restrict__ Wo2, const float* __restrict__ Wv,
                         const float* __restrict__ Wout, __bf16* __restrict__ ws)
{
    int i = blockIdx.x * 256 + threadIdx.x;
    if (i >= 557056) return;
    float v;
    if (i < 131072) {
        int n = i >> 9, k = i & 511;
        v = (k < 256) ? Wq[k * 256 + n] : Wpos[(k - 256) * 256 + n];
    } else if (i < 262144) {
        int j = i - 131072, n = j >> 9, k = j & 511;
        v = (k < 256) ? Wk[k * 256 + n] : Wpos[(k - 256) * 256 + n];
    } else if (i < 393216) {
        int j = i - 262144, n = j >> 8, k = j & 255;
        v = Wo1[k * 512 + n];
    } else if (i < 425984) {
        int j = i - 393216, n = j >> 9, k = j & 511;
        v = Wo2[k * 64 + n];
    } else if (i < 491520) {
        int j = i - 425984, n = j >> 8, k = j & 255;
        v = Wv[k * 256 + n];
    } else {
        int j = i - 491520, n = j >> 8, k = j & 255;
        v = Wout[k * 256 + n];
    }
    ws[i] = (__bf16)v;
}

// ============ K1: query/key/pose -> wv [L*8 floats] ============
extern "C" __global__ void __launch_bounds__(256, 2)
k1_attn_weights(const float* __restrict__ query, const float* __restrict__ key,
                const float* __restrict__ pose, const float* __restrict__ refp,
                const __bf16* __restrict__ ws,
                const float* __restrict__ bq, const float* __restrict__ bk,
                const float* __restrict__ bpos, const float* __restrict__ bo1,
                const float* __restrict__ bo2,
                float* __restrict__ wv_g)
{
    const __bf16* WTqp = ws;
    const __bf16* WTkp = ws + 131072;
    const __bf16* WTo1 = ws + 262144;
    const __bf16* WTo2 = ws + 393216;

    __shared__ __attribute__((aligned(16))) __bf16 SA[MT * CC];  // query -> k
    __shared__ __attribute__((aligned(16))) __bf16 SB[MT * CC];  // pose
    __shared__ __attribute__((aligned(16))) __bf16 SC[MT * CC];  // key
    __shared__ __attribute__((aligned(16))) __bf16 SD[MT * CC];  // h1 -> q
    __shared__ float off_s[MT * 64];

    const int tid = threadIdx.x;
    const int lane = tid & 63;
    const int wid = tid >> 6;
    const int r16 = lane & 15;
    const int q4 = lane >> 4;
    const int row0 = blockIdx.x * MT;
    // per-block de-correlation of weight address streams
    const int seq = blockIdx.x >> 3;          // within-XCD launch sequence
    const int rot = seq & 7;                  // K-step rotation
    const int cb = (((wid + seq) & 3)) * 64;  // rotated column-chunk ownership

    f32x4 acc[2][4];
    f32x4 accO[2];

    // P1: stage query, pose
    {
        f32x4 vq[8], vp[8];
        stage_load(query, row0, tid, vq);
        stage_load(pose, row0, tid, vp);
        stage_write(SA, tid, vq);
        stage_write(SB, tid, vp);
    }
    __syncthreads();                                   // B1

    // P2: h1 pass0 -> SD ; issue key loads (retire in P4)
    f32x4 vkey[8];
    stage_load(key, row0, tid, vkey);
    zero4(acc);
    mfma_tile<2, 4, 8>(SA, WTo1, 256, cb, 0, acc, r16, q4, rot);
#pragma unroll
    for (int mf = 0; mf < 2; ++mf)
#pragma unroll
        for (int nf = 0; nf < 4; ++nf) {
            int col = cb + nf * 16 + r16;
            float bias = bo1[col];
#pragma unroll
            for (int r = 0; r < 4; ++r)
                *(__bf16*)((char*)SD + swz(mf * 16 + q4 * 4 + r, col)) =
                    (__bf16)fmaxf(acc[mf][nf][r] + bias, 0.f);
        }
    __syncthreads();                                   // B2

    // P3: off partial (k 0:256), wave owns off-cols [16*wid, +16)
    accO[0] = (f32x4){0.f, 0.f, 0.f, 0.f};
    accO[1] = (f32x4){0.f, 0.f, 0.f, 0.f};
    {
        f32x4 (&aO)[2][1] = *(f32x4(*)[2][1])&accO;
        mfma_tile<2, 1, 8>(SD, WTo2, 512, wid * 16, 0, aO, r16, q4, rot);
    }
    __syncthreads();                                   // B3 (SD reads done)

    // P4: h1 pass1 -> SD ; retire key into SC
    stage_write(SC, tid, vkey);
    zero4(acc);
    mfma_tile<2, 4, 8>(SA, WTo1, 256, 256 + cb, 0, acc, r16, q4, rot);
#pragma unroll
    for (int mf = 0; mf < 2; ++mf)
#pragma unroll
        for (int nf = 0; nf < 4; ++nf) {
            int col = cb + nf * 16 + r16;
            float bias = bo1[256 + col];
#pragma unroll
            for (int r = 0; r < 4; ++r)
                *(__bf16*)((char*)SD + swz(mf * 16 + q4 * 4 + r, col)) =
                    (__bf16)fmaxf(acc[mf][nf][r] + bias, 0.f);
        }
    __syncthreads();                                   // B4

    // P5: off partial (k 256:512); write off_s
    {
        f32x4 (&aO)[2][1] = *(f32x4(*)[2][1])&accO;
        mfma_tile<2, 1, 8>(SD, WTo2, 512, wid * 16, 256, aO, r16, q4, rot);
    }
    {
        int col = wid * 16 + r16;
        float b2 = bo2[col];
#pragma unroll
        for (int mf = 0; mf < 2; ++mf)
#pragma unroll
            for (int r = 0; r < 4; ++r)
                off_s[(mf * 16 + q4 * 4 + r) * 64 + col] = accO[mf][r] + b2;
    }
    __syncthreads();                                   // B5 (off_s ready; SD free)

    // P6: q = [query|pose] @ WTqp -> SD
    zero4(acc);
    mfma_tile<2, 4, 8>(SA, WTqp, 512, cb, 0, acc, r16, q4, rot);
    mfma_tile<2, 4, 8>(SB, WTqp, 512, cb, 256, acc, r16, q4, rot);
#pragma unroll
    for (int mf = 0; mf < 2; ++mf)
#pragma unroll
        for (int nf = 0; nf < 4; ++nf) {
            int col = cb + nf * 16 + r16;
            float bias = bq[col] + bpos[col];
#pragma unroll
            for (int r = 0; r < 4; ++r)
                *(__bf16*)((char*)SD + swz(mf * 16 + q4 * 4 + r, col)) =
                    (__bf16)(acc[mf][nf][r] + bias);
        }
    __syncthreads();                                   // B6 (SA free)

    // P7: k = [key|pose] @ WTkp -> SA
    zero4(acc);
    mfma_tile<2, 4, 8>(SC, WTkp, 512, cb, 0, acc, r16, q4, rot);
    mfma_tile<2, 4, 8>(SB, WTkp, 512, cb, 256, acc, r16, q4, rot);
#pragma unroll
    for (int mf = 0; mf < 2; ++mf)
#pragma unroll
        for (int nf = 0; nf < 4; ++nf) {
            int col = cb + nf * 16 + r16;
            float bias = bk[col] + bpos[col];
#pragma unroll
            for (int r = 0; r < 4; ++r)
                *(__bf16*)((char*)SA + swz(mf * 16 + q4 * 4 + r, col)) =
                    (__bf16)(acc[mf][nf][r] + bias);
        }
    __syncthreads();                                   // B7

    // P8: scalar attention -> wv_g (global, fp32, streaming)
    {
        int t = tid >> 3, h = tid & 7;
        float qk = 0.f;
#pragma unroll
        for (int j = 0; j < 4; ++j) {
            int c = h * 32 + j * 8;
            bf16x8 qv = *(const bf16x8*)((const char*)SD + swz(t, c));
            bf16x8 kv = *(const bf16x8*)((const char*)SA + swz(t, c));
#pragma unroll
            for (int e = 0; e < 8; ++e) qk += (float)qv[e] * (float)kv[e];
        }
        f32x2 rp = __builtin_nontemporal_load((const f32x2*)(refp + (size_t)(row0 + t) * 2));
        float wgt[4], lg[4];
        float m = -1e30f;
#pragma unroll
        for (int kk = 0; kk < 4; ++kk) {
            float2 o = *(const float2*)&off_s[t * 64 + (h * 4 + kk) * 2];
            float cx = rp[0] + o.x - 0.5f, cy = rp[1] + o.y - 0.5f;
            float wx = fmaxf(0.f, 1.f - fabsf(cx));
            float wy = fmaxf(0.f, 1.f - fabsf(cy));
            wgt[kk] = wx * wy;
            lg[kk] = qk * wgt[kk] * 0.17677669529663687f;  // 1/sqrt(32)
            m = fmaxf(m, lg[kk]);
        }
        float s = 0.f, sw = 0.f;
#pragma unroll
        for (int kk = 0; kk < 4; ++kk) {
            float e = __expf(lg[kk] - m);
            s += e;
            sw += e * wgt[kk];
        }
        __builtin_nontemporal_store(sw / s, wv_g + (size_t)(row0 + t) * 8 + h);
    }
}

// ============ K2: value + wv -> out ============
extern "C" __global__ void __launch_bounds__(256, 4)
k2_output(const float* __restrict__ value, const float* __restrict__ wv_g,
          const __bf16* __restrict__ ws,
          const float* __restrict__ bv, const float* __restrict__ bout,
          float* __restrict__ out)
{
    const __bf16* WTv   = ws + 425984;
    const __bf16* WTout = ws + 491520;

    __shared__ __attribute__((aligned(16))) __bf16 SC[MT * 256];  // value
    __shared__ __attribute__((aligned(16))) __bf16 SD[MT * 256];  // o = v*wv
    __shared__ float wv_s[MT * 8];

    const int tid = threadIdx.x;
    const int lane = tid & 63;
    const int wid = tid >> 6;
    const int r16 = lane & 15;
    const int q4 = lane >> 4;
    const int row0 = blockIdx.x * MT;
    const int seq = blockIdx.x >> 3;
    const int rot = seq & 7;
    const int cb = (((wid + seq) & 3)) * 64;

    f32x4 acc[2][4];

    // P1: stage value -> SC, wv tile -> wv_s
    {
        f32x4 vv[8];
        stage_load(value, row0, tid, vv);
        wv_s[tid] = wv_g[(size_t)row0 * 8 + tid];
        stage_write(SC, tid, vv);
    }
    __syncthreads();

    // P2: o = (value @ WTv + bv) * wv -> SD
    zero4(acc);
    mfma_tile<2, 4, 8>(SC, WTv, 256, cb, 0, acc, r16, q4, rot);
#pragma unroll
    for (int mf = 0; mf < 2; ++mf)
#pragma unroll
        for (int nf = 0; nf < 4; ++nf) {
            int col = cb + nf * 16 + r16;
            float bias = bv[col];
#pragma unroll
            for (int r = 0; r < 4; ++r) {
                int row = mf * 16 + q4 * 4 + r;
                float wvv = wv_s[row * 8 + (col >> 5)];
                *(__bf16*)((char*)SD + swz(row, col)) = (__bf16)((acc[mf][nf][r] + bias) * wvv);
            }
        }
    __syncthreads();

    // P3: out = o @ WTout + bout (streaming store)
    zero4(acc);
    mfma_tile<2, 4, 8>(SD, WTout, 256, cb, 0, acc, r16, q4, rot);
#pragma unroll
    for (int mf = 0; mf < 2; ++mf)
#pragma unroll
        for (int nf = 0; nf < 4; ++nf) {
            int col = cb + nf * 16 + r16;
            float bias = bout[col];
#pragma unroll
            for (int r = 0; r < 4; ++r) {
                int row = mf * 16 + q4 * 4 + r;
                __builtin_nontemporal_store(acc[mf][nf][r] + bias,
                                            out + (size_t)(row0 + row) * CC + col);
            }
        }
}

extern "C" void kernel_launch(void* const* d_in, const int* in_sizes, int n_in,
                              void* d_out, int out_size, void* d_ws, size_t ws_size,
                              hipStream_t stream)
{
    const float* query = (const float*)d_in[0];
    const float* key   = (const float*)d_in[1];
    const float* value = (const float*)d_in[2];
    const float* refp  = (const float*)d_in[3];
    const float* pose  = (const float*)d_in[4];
    const float* Wq  = (const float*)d_in[5];  const float* bq   = (const float*)d_in[6];
    const float* Wk  = (const float*)d_in[7];  const float* bk   = (const float*)d_in[8];
    const float* Wv  = (const float*)d_in[9];  const float* bv   = (const float*)d_in[10];
    const float* Wo1 = (const float*)d_in[11]; const float* bo1  = (const float*)d_in[12];
    const float* Wo2 = (const float*)d_in[13]; const float* bo2  = (const float*)d_in[14];
    const float* Wpos= (const float*)d_in[15]; const float* bpos = (const float*)d_in[16];
    const float* Wout= (const float*)d_in[17]; const float* bout = (const float*)d_in[18];

    __bf16* ws = (__bf16*)d_ws;
    float* wv_g = (float*)((char*)d_ws + 1114112);   // 2 MB after weights

    prep_all<<<2176, 256, 0, stream>>>(Wq, Wk, Wpos, Wo1, Wo2, Wv, Wout, ws);

    k1_attn_weights<<<65536 / MT, 256, 0, stream>>>(
        query, key, pose, refp, ws, bq, bk, bpos, bo1, bo2, wv_g);

    k2_output<<<65536 / MT, 256, 0, stream>>>(
        value, wv_g, ws, bv, bout, (float*)d_out);
}

// Round 9
// 164.169 us; speedup vs baseline: 3.5531x; 1.8790x over previous
//
#include <hip/hip_runtime.h>
#include <hip/hip_bf16.h>

typedef __bf16 bf16x8 __attribute__((ext_vector_type(8)));
typedef float f32x4 __attribute__((ext_vector_type(4)));
typedef float f32x2 __attribute__((ext_vector_type(2)));

#define MT 32   // tokens per tile
#define CC 256

// swizzled LDS byte offset for element (r, c) of a [.][256] bf16 tile
__device__ __forceinline__ int swz(int r, int c) {
    return r * 512 + ((c * 2) ^ ((r & 7) << 4));
}

// Per-wave GEMM tile. B operand is FRAGMENT-PACKED: weight matrix stored as
// (nc, kc) tiles of 16 cols x 32 k = 1KB, contiguous, element order lane*8+e
// (lane = q4*16+r16). Each B-load is one contiguous 1KB wave transaction.
//   KC = K/32 tiles along k;  ct = colbase/16;  kt0 = b_k0/32.
template<int MREP, int NREP, int NKS>
__device__ __forceinline__ void mfma_tile(const __bf16* A_lds, const __bf16* __restrict__ WT,
                                          int KC, int ct, int kt0,
                                          f32x4 (&acc)[MREP][NREP], int r16, int q4, int laneoff)
{
#pragma unroll
    for (int ks = 0; ks < NKS; ++ks) {
        int ak = ks * 32 + q4 * 8;
        bf16x8 a[MREP], b[NREP];
#pragma unroll
        for (int mf = 0; mf < MREP; ++mf)
            a[mf] = *(const bf16x8*)((const char*)A_lds + swz(mf * 16 + r16, ak));
#pragma unroll
        for (int nf = 0; nf < NREP; ++nf)
            b[nf] = *(const bf16x8*)(WT + ((size_t)(ct + nf) * KC + kt0 + ks) * 512 + laneoff);
#pragma unroll
        for (int mf = 0; mf < MREP; ++mf)
#pragma unroll
            for (int nf = 0; nf < NREP; ++nf)
                acc[mf][nf] = __builtin_amdgcn_mfma_f32_16x16x32_bf16(a[mf], b[nf], acc[mf][nf], 0, 0, 0);
    }
}

__device__ __forceinline__ void zero4(f32x4 (&acc)[2][4]) {
#pragma unroll
    for (int i = 0; i < 2; ++i)
#pragma unroll
        for (int j = 0; j < 4; ++j)
            acc[i][j] = (f32x4){0.f, 0.f, 0.f, 0.f};
}

// non-temporal staging: activations are single-use streams.
__device__ __forceinline__ void stage_load(const float* __restrict__ src, int row0, int tid,
                                           f32x4 (&v)[8]) {
#pragma unroll
    for (int i = 0; i < 8; ++i) {
        int f = i * 256 + tid;
        int r = f >> 6;
        int c = (f & 63) * 4;
        v[i] = __builtin_nontemporal_load((const f32x4*)(src + (size_t)(row0 + r) * CC + c));
    }
}
__device__ __forceinline__ void stage_write(__bf16* dst, int tid, const f32x4 (&v)[8]) {
#pragma unroll
    for (int i = 0; i < 8; ++i) {
        int f = i * 256 + tid;
        int r = f >> 6;
        int c = (f & 63) * 4;
        union { __bf16 h[4]; unsigned long long u; } uu;
        uu.h[0] = (__bf16)v[i][0]; uu.h[1] = (__bf16)v[i][1];
        uu.h[2] = (__bf16)v[i][2]; uu.h[3] = (__bf16)v[i][3];
        *(unsigned long long*)((char*)dst + swz(r, c)) = uu.u;
    }
}

// weight prep: transpose + bf16 + FRAGMENT-PACK. packed elem offsets (same totals):
//   WTqp @0 (K=512,N=256: k<256 Wq, else Wpos) | WTkp @131072 (same w/ Wk)
//   WTo1 @262144 (K=256,N=512) | WTo2 @393216 (K=512,N=64)
//   WTv @425984 (K=256,N=256) | WTout @491520 (K=256,N=256)
// pack: j -> tile=j>>9, r=j&511, lane=r>>3, e=r&7, q4=lane>>4, r16=lane&15,
//       nc=tile/KC, kc=tile%KC, k=kc*32+q4*8+e, n=nc*16+r16
__global__ void prep_all(const float* __restrict__ Wq, const float* __restrict__ Wk,
                         const float* __restrict__ Wpos, const float* __restrict__ Wo1,
                         const float* __restrict__ Wo2, const float* __restrict__ Wv,
                         const float* __restrict__ Wout, __bf16* __restrict__ ws)
{
    int i = blockIdx.x * 256 + threadIdx.x;
    if (i >= 557056) return;
    int j, K, N;
    const float* S0 = nullptr; const float* S1 = nullptr;  // S1 = pos part (k>=256)
    if (i < 131072)      { j = i;          K = 512; N = 256; S0 = Wq;  S1 = Wpos; }
    else if (i < 262144) { j = i - 131072; K = 512; N = 256; S0 = Wk;  S1 = Wpos; }
    else if (i < 393216) { j = i - 262144; K = 256; N = 512; S0 = Wo1; }
    else if (i < 425984) { j = i - 393216; K = 512; N = 64;  S0 = Wo2; }
    else if (i < 491520) { j = i - 425984; K = 256; N = 256; S0 = Wv; }
    else                 { j = i - 491520; K = 256; N = 256; S0 = Wout; }
    int tile = j >> 9, r = j & 511;
    int lane = r >> 3, e = r & 7;
    int q4 = lane >> 4, r16 = lane & 15;
    int KC = K >> 5;
    int nc = tile / KC, kc = tile - nc * KC;
    int k = kc * 32 + q4 * 8 + e;
    int n = nc * 16 + r16;
    float v;
    if (S1 && k >= 256) v = S1[(size_t)(k - 256) * N + n];
    else                v = S0[(size_t)k * N + n];
    ws[i] = (__bf16)v;
}

// ============ K1: query/key/pose -> wv [L*8 floats] ============
extern "C" __global__ void __launch_bounds__(256, 2)
k1_attn_weights(const float* __restrict__ query, const float* __restrict__ key,
                const float* __restrict__ pose, const float* __restrict__ refp,
                const __bf16* __restrict__ ws,
                const float* __restrict__ bq, const float* __restrict__ bk,
                const float* __restrict__ bpos, const float* __restrict__ bo1,
                const float* __restrict__ bo2,
                float* __restrict__ wv_g)
{
    const __bf16* WTqp = ws;
    const __bf16* WTkp = ws + 131072;
    const __bf16* WTo1 = ws + 262144;
    const __bf16* WTo2 = ws + 393216;

    __shared__ __attribute__((aligned(16))) __bf16 SA[MT * CC];  // query -> k
    __shared__ __attribute__((aligned(16))) __bf16 SB[MT * CC];  // pose
    __shared__ __attribute__((aligned(16))) __bf16 SC[MT * CC];  // key
    __shared__ __attribute__((aligned(16))) __bf16 SD[MT * CC];  // h1 -> q
    __shared__ float off_s[MT * 64];

    const int tid = threadIdx.x;
    const int lane = tid & 63;
    const int wid = tid >> 6;
    const int r16 = lane & 15;
    const int q4 = lane >> 4;
    const int laneoff = lane * 8;
    const int row0 = blockIdx.x * MT;
    const int cb = wid * 64;
    const int ct = wid * 4;   // colbase/16 for 64-col wave slices

    f32x4 acc[2][4];
    f32x4 accO[2];

    // P1: stage query, pose
    {
        f32x4 vq[8], vp[8];
        stage_load(query, row0, tid, vq);
        stage_load(pose, row0, tid, vp);
        stage_write(SA, tid, vq);
        stage_write(SB, tid, vp);
    }
    __syncthreads();                                   // B1

    // P2: h1 pass0 -> SD ; issue key loads (retire in P4)
    f32x4 vkey[8];
    stage_load(key, row0, tid, vkey);
    zero4(acc);
    mfma_tile<2, 4, 8>(SA, WTo1, 8, ct, 0, acc, r16, q4, laneoff);
#pragma unroll
    for (int mf = 0; mf < 2; ++mf)
#pragma unroll
        for (int nf = 0; nf < 4; ++nf) {
            int col = cb + nf * 16 + r16;
            float bias = bo1[col];
#pragma unroll
            for (int r = 0; r < 4; ++r)
                *(__bf16*)((char*)SD + swz(mf * 16 + q4 * 4 + r, col)) =
                    (__bf16)fmaxf(acc[mf][nf][r] + bias, 0.f);
        }
    __syncthreads();                                   // B2

    // P3: off partial (k 0:256), wave owns off-cols [16*wid, +16)
    accO[0] = (f32x4){0.f, 0.f, 0.f, 0.f};
    accO[1] = (f32x4){0.f, 0.f, 0.f, 0.f};
    {
        f32x4 (&aO)[2][1] = *(f32x4(*)[2][1])&accO;
        mfma_tile<2, 1, 8>(SD, WTo2, 16, wid, 0, aO, r16, q4, laneoff);
    }
    __syncthreads();                                   // B3 (SD reads done)

    // P4: h1 pass1 -> SD ; retire key into SC
    stage_write(SC, tid, vkey);
    zero4(acc);
    mfma_tile<2, 4, 8>(SA, WTo1, 8, 16 + ct, 0, acc, r16, q4, laneoff);
#pragma unroll
    for (int mf = 0; mf < 2; ++mf)
#pragma unroll
        for (int nf = 0; nf < 4; ++nf) {
            int col = cb + nf * 16 + r16;
            float bias = bo1[256 + col];
#pragma unroll
            for (int r = 0; r < 4; ++r)
                *(__bf16*)((char*)SD + swz(mf * 16 + q4 * 4 + r, col)) =
                    (__bf16)fmaxf(acc[mf][nf][r] + bias, 0.f);
        }
    __syncthreads();                                   // B4

    // P5: off partial (k 256:512); write off_s
    {
        f32x4 (&aO)[2][1] = *(f32x4(*)[2][1])&accO;
        mfma_tile<2, 1, 8>(SD, WTo2, 16, wid, 8, aO, r16, q4, laneoff);
    }
    {
        int col = wid * 16 + r16;
        float b2 = bo2[col];
#pragma unroll
        for (int mf = 0; mf < 2; ++mf)
#pragma unroll
            for (int r = 0; r < 4; ++r)
                off_s[(mf * 16 + q4 * 4 + r) * 64 + col] = accO[mf][r] + b2;
    }
    __syncthreads();                                   // B5 (off_s ready; SD free)

    // P6: q = [query|pose] @ WTqp -> SD
    zero4(acc);
    mfma_tile<2, 4, 8>(SA, WTqp, 16, ct, 0, acc, r16, q4, laneoff);
    mfma_tile<2, 4, 8>(SB, WTqp, 16, ct, 8, acc, r16, q4, laneoff);
#pragma unroll
    for (int mf = 0; mf < 2; ++mf)
#pragma unroll
        for (int nf = 0; nf < 4; ++nf) {
            int col = cb + nf * 16 + r16;
            float bias = bq[col] + bpos[col];
#pragma unroll
            for (int r = 0; r < 4; ++r)
                *(__bf16*)((char*)SD + swz(mf * 16 + q4 * 4 + r, col)) =
                    (__bf16)(acc[mf][nf][r] + bias);
        }
    __syncthreads();                                   // B6 (SA free)

    // P7: k = [key|pose] @ WTkp -> SA
    zero4(acc);
    mfma_tile<2, 4, 8>(SC, WTkp, 16, ct, 0, acc, r16, q4, laneoff);
    mfma_tile<2, 4, 8>(SB, WTkp, 16, ct, 8, acc, r16, q4, laneoff);
#pragma unroll
    for (int mf = 0; mf < 2; ++mf)
#pragma unroll
        for (int nf = 0; nf < 4; ++nf) {
            int col = cb + nf * 16 + r16;
            float bias = bk[col] + bpos[col];
#pragma unroll
            for (int r = 0; r < 4; ++r)
                *(__bf16*)((char*)SA + swz(mf * 16 + q4 * 4 + r, col)) =
                    (__bf16)(acc[mf][nf][r] + bias);
        }
    __syncthreads();                                   // B7

    // P8: scalar attention -> wv_g (global, fp32, streaming)
    {
        int t = tid >> 3, h = tid & 7;
        float qk = 0.f;
#pragma unroll
        for (int j = 0; j < 4; ++j) {
            int c = h * 32 + j * 8;
            bf16x8 qv = *(const bf16x8*)((const char*)SD + swz(t, c));
            bf16x8 kv = *(const bf16x8*)((const char*)SA + swz(t, c));
#pragma unroll
            for (int e = 0; e < 8; ++e) qk += (float)qv[e] * (float)kv[e];
        }
        f32x2 rp = __builtin_nontemporal_load((const f32x2*)(refp + (size_t)(row0 + t) * 2));
        float wgt[4], lg[4];
        float m = -1e30f;
#pragma unroll
        for (int kk = 0; kk < 4; ++kk) {
            float2 o = *(const float2*)&off_s[t * 64 + (h * 4 + kk) * 2];
            float cx = rp[0] + o.x - 0.5f, cy = rp[1] + o.y - 0.5f;
            float wx = fmaxf(0.f, 1.f - fabsf(cx));
            float wy = fmaxf(0.f, 1.f - fabsf(cy));
            wgt[kk] = wx * wy;
            lg[kk] = qk * wgt[kk] * 0.17677669529663687f;  // 1/sqrt(32)
            m = fmaxf(m, lg[kk]);
        }
        float s = 0.f, sw = 0.f;
#pragma unroll
        for (int kk = 0; kk < 4; ++kk) {
            float e = __expf(lg[kk] - m);
            s += e;
            sw += e * wgt[kk];
        }
        __builtin_nontemporal_store(sw / s, wv_g + (size_t)(row0 + t) * 8 + h);
    }
}

// ============ K2: value + wv -> out ============
extern "C" __global__ void __launch_bounds__(256, 4)
k2_output(const float* __restrict__ value, const float* __restrict__ wv_g,
          const __bf16* __restrict__ ws,
          const float* __restrict__ bv, const float* __restrict__ bout,
          float* __restrict__ out)
{
    const __bf16* WTv   = ws + 425984;
    const __bf16* WTout = ws + 491520;

    __shared__ __attribute__((aligned(16))) __bf16 SC[MT * 256];  // value
    __shared__ __attribute__((aligned(16))) __bf16 SD[MT * 256];  // o = v*wv
    __shared__ float wv_s[MT * 8];

    const int tid = threadIdx.x;
    const int lane = tid & 63;
    const int wid = tid >> 6;
    const int r16 = lane & 15;
    const int q4 = lane >> 4;
    const int laneoff = lane * 8;
    const int row0 = blockIdx.x * MT;
    const int cb = wid * 64;
    const int ct = wid * 4;

    f32x4 acc[2][4];

    // P1: stage value -> SC, wv tile -> wv_s
    {
        f32x4 vv[8];
        stage_load(value, row0, tid, vv);
        wv_s[tid] = wv_g[(size_t)row0 * 8 + tid];
        stage_write(SC, tid, vv);
    }
    __syncthreads();

    // P2: o = (value @ WTv + bv) * wv -> SD
    zero4(acc);
    mfma_tile<2, 4, 8>(SC, WTv, 8, ct, 0, acc, r16, q4, laneoff);
#pragma unroll
    for (int mf = 0; mf < 2; ++mf)
#pragma unroll
        for (int nf = 0; nf < 4; ++nf) {
            int col = cb + nf * 16 + r16;
            float bias = bv[col];
#pragma unroll
            for (int r = 0; r < 4; ++r) {
                int row = mf * 16 + q4 * 4 + r;
                float wvv = wv_s[row * 8 + (col >> 5)];
                *(__bf16*)((char*)SD + swz(row, col)) = (__bf16)((acc[mf][nf][r] + bias) * wvv);
            }
        }
    __syncthreads();

    // P3: out = o @ WTout + bout (streaming store)
    zero4(acc);
    mfma_tile<2, 4, 8>(SD, WTout, 8, ct, 0, acc, r16, q4, laneoff);
#pragma unroll
    for (int mf = 0; mf < 2; ++mf)
#pragma unroll
        for (int nf = 0; nf < 4; ++nf) {
            int col = cb + nf * 16 + r16;
            float bias = bout[col];
#pragma unroll
            for (int r = 0; r < 4; ++r) {
                int row = mf * 16 + q4 * 4 + r;
                __builtin_nontemporal_store(acc[mf][nf][r] + bias,
                                            out + (size_t)(row0 + row) * CC + col);
            }
        }
}

extern "C" void kernel_launch(void* const* d_in, const int* in_sizes, int n_in,
                              void* d_out, int out_size, void* d_ws, size_t ws_size,
                              hipStream_t stream)
{
    const float* query = (const float*)d_in[0];
    const float* key   = (const float*)d_in[1];
    const float* value = (const float*)d_in[2];
    const float* refp  = (const float*)d_in[3];
    const float* pose  = (const float*)d_in[4];
    const float* Wq  = (const float*)d_in[5];  const float* bq   = (const float*)d_in[6];
    const float* Wk  = (const float*)d_in[7];  const float* bk   = (const float*)d_in[8];
    const float* Wv  = (const float*)d_in[9];  const float* bv   = (const float*)d_in[10];
    const float* Wo1 = (const float*)d_in[11]; const float* bo1  = (const float*)d_in[12];
    const float* Wo2 = (const float*)d_in[13]; const float* bo2  = (const float*)d_in[14];
    const float* Wpos= (const float*)d_in[15]; const float* bpos = (const float*)d_in[16];
    const float* Wout= (const float*)d_in[17]; const float* bout = (const float*)d_in[18];

    __bf16* ws = (__bf16*)d_ws;
    float* wv_g = (float*)((char*)d_ws + 1114112);   // 2 MB after weights

    prep_all<<<2176, 256, 0, stream>>>(Wq, Wk, Wpos, Wo1, Wo2, Wv, Wout, ws);

    k1_attn_weights<<<65536 / MT, 256, 0, stream>>>(
        query, key, pose, refp, ws, bq, bk, bpos, bo1, bo2, wv_g);

    k2_output<<<65536 / MT, 256, 0, stream>>>(
        value, wv_g, ws, bv, bout, (float*)d_out);
}

// Round 10
// 150.538 us; speedup vs baseline: 3.8748x; 1.0906x over previous
//
#include <hip/hip_runtime.h>
#include <hip/hip_bf16.h>

typedef __bf16 bf16x8 __attribute__((ext_vector_type(8)));
typedef float f32x4 __attribute__((ext_vector_type(4)));
typedef float f32x2 __attribute__((ext_vector_type(2)));

#define MT 32   // tokens per block
#define CC 256

// swizzled LDS byte offset, [.][256] bf16 tile (row stride 512B)
__device__ __forceinline__ int swz(int r, int c) {
    return r * 512 + ((c * 2) ^ ((r & 7) << 4));
}
// swizzled LDS byte offset, [.][512] bf16 tile (row stride 1024B)
__device__ __forceinline__ int swzH(int r, int c) {
    return r * 1024 + ((c * 2) ^ ((r & 7) << 4));
}

__device__ __forceinline__ void zero4(f32x4 (&acc)[2][4]) {
#pragma unroll
    for (int i = 0; i < 2; ++i)
#pragma unroll
        for (int j = 0; j < 4; ++j)
            acc[i][j] = (f32x4){0.f, 0.f, 0.f, 0.f};
}

// non-temporal staging loads (single-use activation streams)
__device__ __forceinline__ void stage_load(const float* __restrict__ src, int row0, int tid,
                                           f32x4 (&v)[8]) {
#pragma unroll
    for (int i = 0; i < 8; ++i) {
        int f = i * 256 + tid;
        int r = f >> 6;
        int c = (f & 63) * 4;
        v[i] = __builtin_nontemporal_load((const f32x4*)(src + (size_t)(row0 + r) * CC + c));
    }
}
__device__ __forceinline__ void stage_write(__bf16* dst, int tid, const f32x4 (&v)[8]) {
#pragma unroll
    for (int i = 0; i < 8; ++i) {
        int f = i * 256 + tid;
        int r = f >> 6;
        int c = (f & 63) * 4;
        union { __bf16 h[4]; unsigned long long u; } uu;
        uu.h[0] = (__bf16)v[i][0]; uu.h[1] = (__bf16)v[i][1];
        uu.h[2] = (__bf16)v[i][2]; uu.h[3] = (__bf16)v[i][3];
        *(unsigned long long*)((char*)dst + swz(r, c)) = uu.u;
    }
}

// weight prep: transpose + bf16 + FRAGMENT-PACK (16col x 32k tiles = 1KB contiguous,
// element order lane*8+e). layout (bf16 elem offsets):
//   WTqp @0 (K=512,N=256: k<256 Wq else Wpos) | WTkp @131072 (Wk/Wpos)
//   WTo1 @262144 (K=256,N=512) | WTo2 @393216 (K=512,N=64)
//   WTv @425984 (K=256,N=256) | WTout @491520 (K=256,N=256)
__global__ void prep_all(const float* __restrict__ Wq, const float* __restrict__ Wk,
                         const float* __restrict__ Wpos, const float* __restrict__ Wo1,
                         const float* __restrict__ Wo2, const float* __restrict__ Wv,
                         const float* __restrict__ Wout, __bf16* __restrict__ ws)
{
    int i = blockIdx.x * 256 + threadIdx.x;
    if (i >= 557056) return;
    int j, K, N;
    const float* S0 = nullptr; const float* S1 = nullptr;
    if (i < 131072)      { j = i;          K = 512; N = 256; S0 = Wq;  S1 = Wpos; }
    else if (i < 262144) { j = i - 131072; K = 512; N = 256; S0 = Wk;  S1 = Wpos; }
    else if (i < 393216) { j = i - 262144; K = 256; N = 512; S0 = Wo1; }
    else if (i < 425984) { j = i - 393216; K = 512; N = 64;  S0 = Wo2; }
    else if (i < 491520) { j = i - 425984; K = 256; N = 256; S0 = Wv; }
    else                 { j = i - 491520; K = 256; N = 256; S0 = Wout; }
    int tile = j >> 9, r = j & 511;
    int lane = r >> 3, e = r & 7;
    int q4 = lane >> 4, r16 = lane & 15;
    int KC = K >> 5;
    int nc = tile / KC, kc = tile - nc * KC;
    int k = kc * 32 + q4 * 8 + e;
    int n = nc * 16 + r16;
    float v;
    if (S1 && k >= 256) v = S1[(size_t)(k - 256) * N + n];
    else                v = S0[(size_t)k * N + n];
    ws[i] = (__bf16)v;
}

// ============ single fused kernel: 7 phase slots, 6 barriers ============
extern "C" __global__ void __launch_bounds__(256, 2)
fused_ext_attn(const float* __restrict__ query, const float* __restrict__ key,
               const float* __restrict__ value, const float* __restrict__ refp,
               const float* __restrict__ pose,
               const __bf16* __restrict__ ws,
               const float* __restrict__ bq, const float* __restrict__ bk,
               const float* __restrict__ bv, const float* __restrict__ bpos,
               const float* __restrict__ bo1, const float* __restrict__ bo2,
               const float* __restrict__ bout,
               float* __restrict__ out)
{
    const __bf16* WTqp  = ws;             // KC=16
    const __bf16* WTkp  = ws + 131072;    // KC=16
    const __bf16* WTo1  = ws + 262144;    // KC=8
    const __bf16* WTo2  = ws + 393216;    // KC=16
    const __bf16* WTv   = ws + 425984;    // KC=8
    const __bf16* WTout = ws + 491520;    // KC=8

    __shared__ __attribute__((aligned(16))) __bf16 SA[MT * CC];   // query -> value
    __shared__ __attribute__((aligned(16))) __bf16 SB[MT * CC];   // pose
    __shared__ __attribute__((aligned(16))) __bf16 SC[MT * CC];   // key -> o
    __shared__ __attribute__((aligned(16))) char   H1[32768];     // h1[32][512] -> off/qk/wv

    float* off_s = (float*)H1;            // [32][64] fp32 @ +0   (after B3)
    float* qk_s  = (float*)(H1 + 8192);   // [32][8]        @ +8K
    float* wv_s  = (float*)(H1 + 9216);   // [32][8]        @ +9K

    const int tid = threadIdx.x;
    const int lane = tid & 63;
    const int wid = tid >> 6;
    const int r16 = lane & 15;
    const int q4 = lane >> 4;
    const int laneoff = lane * 8;
    const int row0 = blockIdx.x * MT;

    // ---- P1: issue query/pose/key loads; stage query->SA, pose->SB ----
    f32x4 vq[8], vp[8], vkey[8];
    stage_load(query, row0, tid, vq);
    stage_load(pose, row0, tid, vp);
    stage_load(key, row0, tid, vkey);
    stage_write(SA, tid, vq);
    stage_write(SB, tid, vp);
    __syncthreads();                                   // B1

    // ---- P2: retire key->SC ; h1 = relu(query@Wo1+bo1), full 512 cols -> H1 ----
    stage_write(SC, tid, vkey);
    {
        f32x4 acc[2][8];
#pragma unroll
        for (int i = 0; i < 2; ++i)
#pragma unroll
            for (int j = 0; j < 8; ++j) acc[i][j] = (f32x4){0.f, 0.f, 0.f, 0.f};
#pragma unroll
        for (int ks = 0; ks < 8; ++ks) {
            int ak = ks * 32 + q4 * 8;
            bf16x8 a[2], b[8];
#pragma unroll
            for (int mf = 0; mf < 2; ++mf)
                a[mf] = *(const bf16x8*)((const char*)SA + swz(mf * 16 + r16, ak));
#pragma unroll
            for (int nf = 0; nf < 8; ++nf)
                b[nf] = *(const bf16x8*)(WTo1 + ((size_t)(wid * 8 + nf) * 8 + ks) * 512 + laneoff);
#pragma unroll
            for (int mf = 0; mf < 2; ++mf)
#pragma unroll
                for (int nf = 0; nf < 8; ++nf)
                    acc[mf][nf] = __builtin_amdgcn_mfma_f32_16x16x32_bf16(a[mf], b[nf], acc[mf][nf], 0, 0, 0);
        }
#pragma unroll
        for (int mf = 0; mf < 2; ++mf)
#pragma unroll
            for (int nf = 0; nf < 8; ++nf) {
                int col = wid * 128 + nf * 16 + r16;
                float bias = bo1[col];
#pragma unroll
                for (int r = 0; r < 4; ++r)
                    *(__bf16*)(H1 + swzH(mf * 16 + q4 * 4 + r, col)) =
                        (__bf16)fmaxf(acc[mf][nf][r] + bias, 0.f);
            }
    }
    __syncthreads();                                   // B2

    // ---- P3: off = h1 @ Wo2 (K=512), wave owns off-cols [16w,16w+16) -> regs ----
    f32x4 accO[2];
    accO[0] = (f32x4){0.f, 0.f, 0.f, 0.f};
    accO[1] = (f32x4){0.f, 0.f, 0.f, 0.f};
#pragma unroll
    for (int ks = 0; ks < 16; ++ks) {
        int ak = ks * 32 + q4 * 8;
        bf16x8 b = *(const bf16x8*)(WTo2 + ((size_t)wid * 16 + ks) * 512 + laneoff);
#pragma unroll
        for (int mf = 0; mf < 2; ++mf) {
            bf16x8 a = *(const bf16x8*)(H1 + swzH(mf * 16 + r16, ak));
            accO[mf] = __builtin_amdgcn_mfma_f32_16x16x32_bf16(a, b, accO[mf], 0, 0, 0);
        }
    }
    __syncthreads();                                   // B3 (H1 dead; scalars may alias)

    // ---- P4: off_s write ; issue value loads ; q/k GEMMs in-reg ; dot ; softmax ----
    {
        int col = wid * 16 + r16;
        float b2 = bo2[col];
#pragma unroll
        for (int mf = 0; mf < 2; ++mf)
#pragma unroll
            for (int r = 0; r < 4; ++r)
                off_s[(mf * 16 + q4 * 4 + r) * 64 + col] = accO[mf][r] + b2;
    }
    f32x4 vval[8];
    stage_load(value, row0, tid, vval);   // retires after B4 (hidden under 256 MFMA)
    {
        f32x4 qa[2][4], ka[2][4];
        zero4(qa); zero4(ka);
#pragma unroll
        for (int ks = 0; ks < 8; ++ks) {   // k-slice 0:256 — A = query / key
            int ak = ks * 32 + q4 * 8;
            bf16x8 aq[2], akk[2];
#pragma unroll
            for (int mf = 0; mf < 2; ++mf) {
                aq[mf]  = *(const bf16x8*)((const char*)SA + swz(mf * 16 + r16, ak));
                akk[mf] = *(const bf16x8*)((const char*)SC + swz(mf * 16 + r16, ak));
            }
#pragma unroll
            for (int nf = 0; nf < 4; ++nf) {
                size_t toff = ((size_t)(wid * 4 + nf) * 16 + ks) * 512 + laneoff;
                bf16x8 bqf = *(const bf16x8*)(WTqp + toff);
                bf16x8 bkf = *(const bf16x8*)(WTkp + toff);
#pragma unroll
                for (int mf = 0; mf < 2; ++mf) {
                    qa[mf][nf] = __builtin_amdgcn_mfma_f32_16x16x32_bf16(aq[mf],  bqf, qa[mf][nf], 0, 0, 0);
                    ka[mf][nf] = __builtin_amdgcn_mfma_f32_16x16x32_bf16(akk[mf], bkf, ka[mf][nf], 0, 0, 0);
                }
            }
        }
#pragma unroll
        for (int ks = 8; ks < 16; ++ks) {  // k-slice 256:512 — A = pose (shared)
            int ak = (ks - 8) * 32 + q4 * 8;
            bf16x8 ap[2];
#pragma unroll
            for (int mf = 0; mf < 2; ++mf)
                ap[mf] = *(const bf16x8*)((const char*)SB + swz(mf * 16 + r16, ak));
#pragma unroll
            for (int nf = 0; nf < 4; ++nf) {
                size_t toff = ((size_t)(wid * 4 + nf) * 16 + ks) * 512 + laneoff;
                bf16x8 bqf = *(const bf16x8*)(WTqp + toff);
                bf16x8 bkf = *(const bf16x8*)(WTkp + toff);
#pragma unroll
                for (int mf = 0; mf < 2; ++mf) {
                    qa[mf][nf] = __builtin_amdgcn_mfma_f32_16x16x32_bf16(ap[mf], bqf, qa[mf][nf], 0, 0, 0);
                    ka[mf][nf] = __builtin_amdgcn_mfma_f32_16x16x32_bf16(ap[mf], bkf, ka[mf][nf], 0, 0, 0);
                }
            }
        }
        // biases + wave-local head dot (wave cols 64w..64w+64 = heads 2w,2w+1)
        float Bq[4], Bk[4];
#pragma unroll
        for (int nf = 0; nf < 4; ++nf) {
            int col = wid * 64 + nf * 16 + r16;
            Bq[nf] = bq[col] + bpos[col];
            Bk[nf] = bk[col] + bpos[col];
        }
#pragma unroll
        for (int mf = 0; mf < 2; ++mf)
#pragma unroll
            for (int r = 0; r < 4; ++r) {
                float p0 = (qa[mf][0][r] + Bq[0]) * (ka[mf][0][r] + Bk[0])
                         + (qa[mf][1][r] + Bq[1]) * (ka[mf][1][r] + Bk[1]);
                float p1 = (qa[mf][2][r] + Bq[2]) * (ka[mf][2][r] + Bk[2])
                         + (qa[mf][3][r] + Bq[3]) * (ka[mf][3][r] + Bk[3]);
#pragma unroll
                for (int m = 1; m < 16; m <<= 1) {
                    p0 += __shfl_xor(p0, m);
                    p1 += __shfl_xor(p1, m);
                }
                if (r16 == 0) {
                    int row = mf * 16 + q4 * 4 + r;
                    f32x2 pq = {p0, p1};
                    *(f32x2*)&qk_s[row * 8 + wid * 2] = pq;
                }
            }
    }
    // intra-wave fence: off_s + qk_s writes visible to this wave's lanes
    asm volatile("s_waitcnt lgkmcnt(0)" ::: "memory");
    __builtin_amdgcn_sched_barrier(0);
    {
        // 64 jobs per wave: lane l -> token t=l>>1, head h=2*wid+(l&1)
        int t = lane >> 1, h = wid * 2 + (lane & 1);
        float qk = qk_s[t * 8 + h];
        f32x2 rp = __builtin_nontemporal_load((const f32x2*)(refp + (size_t)(row0 + t) * 2));
        float wgt[4], lg[4];
        float m = -1e30f;
#pragma unroll
        for (int kk = 0; kk < 4; ++kk) {
            float ox = off_s[t * 64 + (h * 4 + kk) * 2];
            float oy = off_s[t * 64 + (h * 4 + kk) * 2 + 1];
            float cx = rp[0] + ox - 0.5f, cy = rp[1] + oy - 0.5f;
            float wx = fmaxf(0.f, 1.f - fabsf(cx));
            float wy = fmaxf(0.f, 1.f - fabsf(cy));
            wgt[kk] = wx * wy;
            lg[kk] = qk * wgt[kk] * 0.17677669529663687f;  // 1/sqrt(32)
            m = fmaxf(m, lg[kk]);
        }
        float s = 0.f, sw = 0.f;
#pragma unroll
        for (int kk = 0; kk < 4; ++kk) {
            float e = __expf(lg[kk] - m);
            s += e;
            sw += e * wgt[kk];
        }
        wv_s[t * 8 + h] = sw / s;
    }
    __syncthreads();                                   // B4 (SA/SC reads drained)

    // ---- P4b: retire value -> SA ----
    stage_write(SA, tid, vval);
    __syncthreads();                                   // B5

    // ---- P5: o = (value@Wv + bv) * wv -> SC ----
    {
        f32x4 acc[2][4];
        zero4(acc);
#pragma unroll
        for (int ks = 0; ks < 8; ++ks) {
            int ak = ks * 32 + q4 * 8;
            bf16x8 a[2], b[4];
#pragma unroll
            for (int mf = 0; mf < 2; ++mf)
                a[mf] = *(const bf16x8*)((const char*)SA + swz(mf * 16 + r16, ak));
#pragma unroll
            for (int nf = 0; nf < 4; ++nf)
                b[nf] = *(const bf16x8*)(WTv + ((size_t)(wid * 4 + nf) * 8 + ks) * 512 + laneoff);
#pragma unroll
            for (int mf = 0; mf < 2; ++mf)
#pragma unroll
                for (int nf = 0; nf < 4; ++nf)
                    acc[mf][nf] = __builtin_amdgcn_mfma_f32_16x16x32_bf16(a[mf], b[nf], acc[mf][nf], 0, 0, 0);
        }
#pragma unroll
        for (int mf = 0; mf < 2; ++mf)
#pragma unroll
            for (int nf = 0; nf < 4; ++nf) {
                int col = wid * 64 + nf * 16 + r16;
                float bias = bv[col];
#pragma unroll
                for (int r = 0; r < 4; ++r) {
                    int row = mf * 16 + q4 * 4 + r;
                    float wvv = wv_s[row * 8 + (col >> 5)];
                    *(__bf16*)((char*)SC + swz(row, col)) = (__bf16)((acc[mf][nf][r] + bias) * wvv);
                }
            }
    }
    __syncthreads();                                   // B6

    // ---- P6: out = o @ WTout + bout -> global (NT store) ----
    {
        f32x4 acc[2][4];
        zero4(acc);
#pragma unroll
        for (int ks = 0; ks < 8; ++ks) {
            int ak = ks * 32 + q4 * 8;
            bf16x8 a[2], b[4];
#pragma unroll
            for (int mf = 0; mf < 2; ++mf)
                a[mf] = *(const bf16x8*)((const char*)SC + swz(mf * 16 + r16, ak));
#pragma unroll
            for (int nf = 0; nf < 4; ++nf)
                b[nf] = *(const bf16x8*)(WTout + ((size_t)(wid * 4 + nf) * 8 + ks) * 512 + laneoff);
#pragma unroll
            for (int mf = 0; mf < 2; ++mf)
#pragma unroll
                for (int nf = 0; nf < 4; ++nf)
                    acc[mf][nf] = __builtin_amdgcn_mfma_f32_16x16x32_bf16(a[mf], b[nf], acc[mf][nf], 0, 0, 0);
        }
#pragma unroll
        for (int mf = 0; mf < 2; ++mf)
#pragma unroll
            for (int nf = 0; nf < 4; ++nf) {
                int col = wid * 64 + nf * 16 + r16;
                float bias = bout[col];
#pragma unroll
                for (int r = 0; r < 4; ++r) {
                    int row = mf * 16 + q4 * 4 + r;
                    __builtin_nontemporal_store(acc[mf][nf][r] + bias,
                                                out + (size_t)(row0 + row) * CC + col);
                }
            }
    }
}

extern "C" void kernel_launch(void* const* d_in, const int* in_sizes, int n_in,
                              void* d_out, int out_size, void* d_ws, size_t ws_size,
                              hipStream_t stream)
{
    const float* query = (const float*)d_in[0];
    const float* key   = (const float*)d_in[1];
    const float* value = (const float*)d_in[2];
    const float* refp  = (const float*)d_in[3];
    const float* pose  = (const float*)d_in[4];
    const float* Wq  = (const float*)d_in[5];  const float* bq   = (const float*)d_in[6];
    const float* Wk  = (const float*)d_in[7];  const float* bk   = (const float*)d_in[8];
    const float* Wv  = (const float*)d_in[9];  const float* bv   = (const float*)d_in[10];
    const float* Wo1 = (const float*)d_in[11]; const float* bo1  = (const float*)d_in[12];
    const float* Wo2 = (const float*)d_in[13]; const float* bo2  = (const float*)d_in[14];
    const float* Wpos= (const float*)d_in[15]; const float* bpos = (const float*)d_in[16];
    const float* Wout= (const float*)d_in[17]; const float* bout = (const float*)d_in[18];

    __bf16* ws = (__bf16*)d_ws;

    prep_all<<<2176, 256, 0, stream>>>(Wq, Wk, Wpos, Wo1, Wo2, Wv, Wout, ws);

    fused_ext_attn<<<65536 / MT, 256, 0, stream>>>(
        query, key, value, refp, pose, ws,
        bq, bk, bv, bpos, bo1, bo2, bout, (float*)d_out);
}

// Round 11
// 146.773 us; speedup vs baseline: 3.9742x; 1.0257x over previous
//
#include <hip/hip_runtime.h>
#include <hip/hip_bf16.h>

typedef __bf16 bf16x8 __attribute__((ext_vector_type(8)));
typedef float f32x4 __attribute__((ext_vector_type(4)));
typedef float f32x2 __attribute__((ext_vector_type(2)));

#define MT 32   // tokens per block
#define CC 256

// swizzled LDS byte offset, [.][256] bf16 tile (row stride 512B)
__device__ __forceinline__ int swz(int r, int c) {
    return r * 512 + ((c * 2) ^ ((r & 7) << 4));
}
// swizzled LDS byte offset, [.][512] bf16 tile (row stride 1024B)
__device__ __forceinline__ int swzH(int r, int c) {
    return r * 1024 + ((c * 2) ^ ((r & 7) << 4));
}

// 512-thread staging of a 32x256 fp32 tile (4 f32x4 per thread), NT loads
__device__ __forceinline__ void stage_load(const float* __restrict__ src, int row0, int tid,
                                           f32x4 (&v)[4]) {
#pragma unroll
    for (int i = 0; i < 4; ++i) {
        int f = i * 512 + tid;
        int r = f >> 6;
        int c = (f & 63) * 4;
        v[i] = __builtin_nontemporal_load((const f32x4*)(src + (size_t)(row0 + r) * CC + c));
    }
}
__device__ __forceinline__ void stage_write(__bf16* dst, int tid, const f32x4 (&v)[4]) {
#pragma unroll
    for (int i = 0; i < 4; ++i) {
        int f = i * 512 + tid;
        int r = f >> 6;
        int c = (f & 63) * 4;
        union { __bf16 h[4]; unsigned long long u; } uu;
        uu.h[0] = (__bf16)v[i][0]; uu.h[1] = (__bf16)v[i][1];
        uu.h[2] = (__bf16)v[i][2]; uu.h[3] = (__bf16)v[i][3];
        *(unsigned long long*)((char*)dst + swz(r, c)) = uu.u;
    }
}

// weight prep: transpose + bf16 + FRAGMENT-PACK (16col x 32k tiles = 1KB contiguous,
// element order lane*8+e). layout (bf16 elem offsets):
//   WTqp @0 (K=512,N=256: k<256 Wq else Wpos) | WTkp @131072 (Wk/Wpos)
//   WTo1 @262144 (K=256,N=512) | WTo2 @393216 (K=512,N=64)
//   WTv @425984 (K=256,N=256) | WTout @491520 (K=256,N=256)
__global__ void prep_all(const float* __restrict__ Wq, const float* __restrict__ Wk,
                         const float* __restrict__ Wpos, const float* __restrict__ Wo1,
                         const float* __restrict__ Wo2, const float* __restrict__ Wv,
                         const float* __restrict__ Wout, __bf16* __restrict__ ws)
{
    int i = blockIdx.x * 256 + threadIdx.x;
    if (i >= 557056) return;
    int j, K, N;
    const float* S0 = nullptr; const float* S1 = nullptr;
    if (i < 131072)      { j = i;          K = 512; N = 256; S0 = Wq;  S1 = Wpos; }
    else if (i < 262144) { j = i - 131072; K = 512; N = 256; S0 = Wk;  S1 = Wpos; }
    else if (i < 393216) { j = i - 262144; K = 256; N = 512; S0 = Wo1; }
    else if (i < 425984) { j = i - 393216; K = 512; N = 64;  S0 = Wo2; }
    else if (i < 491520) { j = i - 425984; K = 256; N = 256; S0 = Wv; }
    else                 { j = i - 491520; K = 256; N = 256; S0 = Wout; }
    int tile = j >> 9, r = j & 511;
    int lane = r >> 3, e = r & 7;
    int q4 = lane >> 4, r16 = lane & 15;
    int KC = K >> 5;
    int nc = tile / KC, kc = tile - nc * KC;
    int k = kc * 32 + q4 * 8 + e;
    int n = nc * 16 + r16;
    float v;
    if (S1 && k >= 256) v = S1[(size_t)(k - 256) * N + n];
    else                v = S0[(size_t)k * N + n];
    ws[i] = (__bf16)v;
}

// ============ single fused kernel: 512 threads (8 waves), 2 blocks/CU = 16 waves/CU ============
extern "C" __global__ void __launch_bounds__(512, 4)
fused_ext_attn(const float* __restrict__ query, const float* __restrict__ key,
               const float* __restrict__ value, const float* __restrict__ refp,
               const float* __restrict__ pose,
               const __bf16* __restrict__ ws,
               const float* __restrict__ bq, const float* __restrict__ bk,
               const float* __restrict__ bv, const float* __restrict__ bpos,
               const float* __restrict__ bo1, const float* __restrict__ bo2,
               const float* __restrict__ bout,
               float* __restrict__ out)
{
    const __bf16* WTqp  = ws;             // KC=16
    const __bf16* WTkp  = ws + 131072;    // KC=16
    const __bf16* WTo1  = ws + 262144;    // KC=8
    const __bf16* WTo2  = ws + 393216;    // KC=16
    const __bf16* WTv   = ws + 425984;    // KC=8
    const __bf16* WTout = ws + 491520;    // KC=8

    __shared__ __attribute__((aligned(16))) __bf16 SA[MT * CC];   // query -> value
    __shared__ __attribute__((aligned(16))) __bf16 SB[MT * CC];   // pose
    __shared__ __attribute__((aligned(16))) __bf16 SC[MT * CC];   // key -> o
    __shared__ __attribute__((aligned(16))) char   H1[32768];     // h1[32][512]; off/qk/wv alias after B3

    float* off_s = (float*)H1;            // [32][64] fp32  (valid after B3b)
    float* qk_s  = (float*)(H1 + 8192);   // [32][8]
    float* wv_s  = (float*)(H1 + 9216);   // [32][8]

    const int tid = threadIdx.x;
    const int lane = tid & 63;
    const int wid = tid >> 6;        // 0..7 — this wave's head for q/k/v phases
    const int r16 = lane & 15;
    const int q4 = lane >> 4;
    const int laneoff = lane * 8;
    const int row0 = blockIdx.x * MT;

    // ---- P1: issue query/pose/key loads; stage query->SA, pose->SB ----
    f32x4 vq[4], vp[4], vkey[4];
    stage_load(query, row0, tid, vq);
    stage_load(pose, row0, tid, vp);
    stage_load(key, row0, tid, vkey);
    stage_write(SA, tid, vq);
    stage_write(SB, tid, vp);
    __syncthreads();                                   // B1

    // ---- P2: retire key->SC ; h1 = relu(query@Wo1+bo1), wave owns 64 cols -> H1 ----
    stage_write(SC, tid, vkey);
    {
        f32x4 acc[2][4];
#pragma unroll
        for (int i = 0; i < 2; ++i)
#pragma unroll
            for (int j = 0; j < 4; ++j) acc[i][j] = (f32x4){0.f, 0.f, 0.f, 0.f};
#pragma unroll
        for (int ks = 0; ks < 8; ++ks) {
            int ak = ks * 32 + q4 * 8;
            bf16x8 a[2], b[4];
#pragma unroll
            for (int mf = 0; mf < 2; ++mf)
                a[mf] = *(const bf16x8*)((const char*)SA + swz(mf * 16 + r16, ak));
#pragma unroll
            for (int nf = 0; nf < 4; ++nf)
                b[nf] = *(const bf16x8*)(WTo1 + ((size_t)(wid * 4 + nf) * 8 + ks) * 512 + laneoff);
#pragma unroll
            for (int mf = 0; mf < 2; ++mf)
#pragma unroll
                for (int nf = 0; nf < 4; ++nf)
                    acc[mf][nf] = __builtin_amdgcn_mfma_f32_16x16x32_bf16(a[mf], b[nf], acc[mf][nf], 0, 0, 0);
        }
#pragma unroll
        for (int mf = 0; mf < 2; ++mf)
#pragma unroll
            for (int nf = 0; nf < 4; ++nf) {
                int col = wid * 64 + nf * 16 + r16;
                float bias = bo1[col];
#pragma unroll
                for (int r = 0; r < 4; ++r)
                    *(__bf16*)(H1 + swzH(mf * 16 + q4 * 4 + r, col)) =
                        (__bf16)fmaxf(acc[mf][nf][r] + bias, 0.f);
            }
    }
    __syncthreads();                                   // B2

    // ---- P3: merged phase. waves 0-3: off prelude (16 off-cols each, K=512).
    //          all waves: q/k GEMM for head wid (32 cols), in registers. ----
    f32x4 accO[2];
    accO[0] = (f32x4){0.f, 0.f, 0.f, 0.f};
    accO[1] = (f32x4){0.f, 0.f, 0.f, 0.f};
    if (wid < 4) {
#pragma unroll
        for (int ks = 0; ks < 16; ++ks) {
            int ak = ks * 32 + q4 * 8;
            bf16x8 b = *(const bf16x8*)(WTo2 + ((size_t)wid * 16 + ks) * 512 + laneoff);
#pragma unroll
            for (int mf = 0; mf < 2; ++mf) {
                bf16x8 a = *(const bf16x8*)(H1 + swzH(mf * 16 + r16, ak));
                accO[mf] = __builtin_amdgcn_mfma_f32_16x16x32_bf16(a, b, accO[mf], 0, 0, 0);
            }
        }
    }
    // issue value loads (retire after B3, hidden under q/k MFMAs)
    f32x4 vval[4];
    stage_load(value, row0, tid, vval);
    float qk_r[2][4];
    {
        f32x4 qa[2][2], ka[2][2];
#pragma unroll
        for (int i = 0; i < 2; ++i)
#pragma unroll
            for (int j = 0; j < 2; ++j) {
                qa[i][j] = (f32x4){0.f, 0.f, 0.f, 0.f};
                ka[i][j] = (f32x4){0.f, 0.f, 0.f, 0.f};
            }
#pragma unroll
        for (int ks = 0; ks < 8; ++ks) {   // k-slice 0:256 — A = query / key
            int ak = ks * 32 + q4 * 8;
            bf16x8 aq[2], akk[2];
#pragma unroll
            for (int mf = 0; mf < 2; ++mf) {
                aq[mf]  = *(const bf16x8*)((const char*)SA + swz(mf * 16 + r16, ak));
                akk[mf] = *(const bf16x8*)((const char*)SC + swz(mf * 16 + r16, ak));
            }
#pragma unroll
            for (int nf = 0; nf < 2; ++nf) {
                size_t toff = ((size_t)(wid * 2 + nf) * 16 + ks) * 512 + laneoff;
                bf16x8 bqf = *(const bf16x8*)(WTqp + toff);
                bf16x8 bkf = *(const bf16x8*)(WTkp + toff);
#pragma unroll
                for (int mf = 0; mf < 2; ++mf) {
                    qa[mf][nf] = __builtin_amdgcn_mfma_f32_16x16x32_bf16(aq[mf],  bqf, qa[mf][nf], 0, 0, 0);
                    ka[mf][nf] = __builtin_amdgcn_mfma_f32_16x16x32_bf16(akk[mf], bkf, ka[mf][nf], 0, 0, 0);
                }
            }
        }
#pragma unroll
        for (int ks = 8; ks < 16; ++ks) {  // k-slice 256:512 — A = pose (shared q/k)
            int ak = (ks - 8) * 32 + q4 * 8;
            bf16x8 ap[2];
#pragma unroll
            for (int mf = 0; mf < 2; ++mf)
                ap[mf] = *(const bf16x8*)((const char*)SB + swz(mf * 16 + r16, ak));
#pragma unroll
            for (int nf = 0; nf < 2; ++nf) {
                size_t toff = ((size_t)(wid * 2 + nf) * 16 + ks) * 512 + laneoff;
                bf16x8 bqf = *(const bf16x8*)(WTqp + toff);
                bf16x8 bkf = *(const bf16x8*)(WTkp + toff);
#pragma unroll
                for (int mf = 0; mf < 2; ++mf) {
                    qa[mf][nf] = __builtin_amdgcn_mfma_f32_16x16x32_bf16(ap[mf], bqf, qa[mf][nf], 0, 0, 0);
                    ka[mf][nf] = __builtin_amdgcn_mfma_f32_16x16x32_bf16(ap[mf], bkf, ka[mf][nf], 0, 0, 0);
                }
            }
        }
        // bias + wave-local head dot (wave cols = head wid), butterfly over 16-lane group
        float Bq[2], Bk[2];
#pragma unroll
        for (int nf = 0; nf < 2; ++nf) {
            int col = wid * 32 + nf * 16 + r16;
            Bq[nf] = bq[col] + bpos[col];
            Bk[nf] = bk[col] + bpos[col];
        }
#pragma unroll
        for (int mf = 0; mf < 2; ++mf)
#pragma unroll
            for (int r = 0; r < 4; ++r) {
                float p0 = (qa[mf][0][r] + Bq[0]) * (ka[mf][0][r] + Bk[0])
                         + (qa[mf][1][r] + Bq[1]) * (ka[mf][1][r] + Bk[1]);
#pragma unroll
                for (int m = 1; m < 16; m <<= 1)
                    p0 += __shfl_xor(p0, m);
                qk_r[mf][r] = p0;
            }
    }
    __syncthreads();                                   // B3 (H1, SA dead)

    // ---- P3b: retire value->SA ; write off_s (waves 0-3) + qk_s into H1 alias ----
    stage_write(SA, tid, vval);
    if (wid < 4) {
        int col = wid * 16 + r16;
        float b2 = bo2[col];
#pragma unroll
        for (int mf = 0; mf < 2; ++mf)
#pragma unroll
            for (int r = 0; r < 4; ++r)
                off_s[(mf * 16 + q4 * 4 + r) * 64 + col] = accO[mf][r] + b2;
    }
    if (r16 == 0) {
#pragma unroll
        for (int mf = 0; mf < 2; ++mf)
#pragma unroll
            for (int r = 0; r < 4; ++r)
                qk_s[(mf * 16 + q4 * 4 + r) * 8 + wid] = qk_r[mf][r];
    }
    __syncthreads();                                   // B3b

    // ---- P4: softmax -> wv_s (256 jobs on first 256 threads) ----
    if (tid < 256) {
        int t = tid >> 3, h = tid & 7;
        float qk = qk_s[t * 8 + h];
        f32x2 rp = __builtin_nontemporal_load((const f32x2*)(refp + (size_t)(row0 + t) * 2));
        float wgt[4], lg[4];
        float m = -1e30f;
#pragma unroll
        for (int kk = 0; kk < 4; ++kk) {
            float ox = off_s[t * 64 + (h * 4 + kk) * 2];
            float oy = off_s[t * 64 + (h * 4 + kk) * 2 + 1];
            float cx = rp[0] + ox - 0.5f, cy = rp[1] + oy - 0.5f;
            float wx = fmaxf(0.f, 1.f - fabsf(cx));
            float wy = fmaxf(0.f, 1.f - fabsf(cy));
            wgt[kk] = wx * wy;
            lg[kk] = qk * wgt[kk] * 0.17677669529663687f;  // 1/sqrt(32)
            m = fmaxf(m, lg[kk]);
        }
        float s = 0.f, sw = 0.f;
#pragma unroll
        for (int kk = 0; kk < 4; ++kk) {
            float e = __expf(lg[kk] - m);
            s += e;
            sw += e * wgt[kk];
        }
        wv_s[t * 8 + h] = sw / s;
    }
    __syncthreads();                                   // B4

    // ---- P5: o = (value@Wv + bv) * wv -> SC (wave cols = head wid) ----
    {
        f32x4 acc[2][2];
#pragma unroll
        for (int i = 0; i < 2; ++i)
#pragma unroll
            for (int j = 0; j < 2; ++j) acc[i][j] = (f32x4){0.f, 0.f, 0.f, 0.f};
#pragma unroll
        for (int ks = 0; ks < 8; ++ks) {
            int ak = ks * 32 + q4 * 8;
            bf16x8 a[2], b[2];
#pragma unroll
            for (int mf = 0; mf < 2; ++mf)
                a[mf] = *(const bf16x8*)((const char*)SA + swz(mf * 16 + r16, ak));
#pragma unroll
            for (int nf = 0; nf < 2; ++nf)
                b[nf] = *(const bf16x8*)(WTv + ((size_t)(wid * 2 + nf) * 8 + ks) * 512 + laneoff);
#pragma unroll
            for (int mf = 0; mf < 2; ++mf)
#pragma unroll
                for (int nf = 0; nf < 2; ++nf)
                    acc[mf][nf] = __builtin_amdgcn_mfma_f32_16x16x32_bf16(a[mf], b[nf], acc[mf][nf], 0, 0, 0);
        }
#pragma unroll
        for (int mf = 0; mf < 2; ++mf)
#pragma unroll
            for (int nf = 0; nf < 2; ++nf) {
                int col = wid * 32 + nf * 16 + r16;
                float bias = bv[col];
#pragma unroll
                for (int r = 0; r < 4; ++r) {
                    int row = mf * 16 + q4 * 4 + r;
                    float wvv = wv_s[row * 8 + wid];
                    *(__bf16*)((char*)SC + swz(row, col)) = (__bf16)((acc[mf][nf][r] + bias) * wvv);
                }
            }
    }
    __syncthreads();                                   // B5

    // ---- P6: out = o @ WTout + bout -> global (NT store) ----
    {
        f32x4 acc[2][2];
#pragma unroll
        for (int i = 0; i < 2; ++i)
#pragma unroll
            for (int j = 0; j < 2; ++j) acc[i][j] = (f32x4){0.f, 0.f, 0.f, 0.f};
#pragma unroll
        for (int ks = 0; ks < 8; ++ks) {
            int ak = ks * 32 + q4 * 8;
            bf16x8 a[2], b[2];
#pragma unroll
            for (int mf = 0; mf < 2; ++mf)
                a[mf] = *(const bf16x8*)((const char*)SC + swz(mf * 16 + r16, ak));
#pragma unroll
            for (int nf = 0; nf < 2; ++nf)
                b[nf] = *(const bf16x8*)(WTout + ((size_t)(wid * 2 + nf) * 8 + ks) * 512 + laneoff);
#pragma unroll
            for (int mf = 0; mf < 2; ++mf)
#pragma unroll
                for (int nf = 0; nf < 2; ++nf)
                    acc[mf][nf] = __builtin_amdgcn_mfma_f32_16x16x32_bf16(a[mf], b[nf], acc[mf][nf], 0, 0, 0);
        }
#pragma unroll
        for (int mf = 0; mf < 2; ++mf)
#pragma unroll
            for (int nf = 0; nf < 2; ++nf) {
                int col = wid * 32 + nf * 16 + r16;
                float bias = bout[col];
#pragma unroll
                for (int r = 0; r < 4; ++r) {
                    int row = mf * 16 + q4 * 4 + r;
                    __builtin_nontemporal_store(acc[mf][nf][r] + bias,
                                                out + (size_t)(row0 + row) * CC + col);
                }
            }
    }
}

extern "C" void kernel_launch(void* const* d_in, const int* in_sizes, int n_in,
                              void* d_out, int out_size, void* d_ws, size_t ws_size,
                              hipStream_t stream)
{
    const float* query = (const float*)d_in[0];
    const float* key   = (const float*)d_in[1];
    const float* value = (const float*)d_in[2];
    const float* refp  = (const float*)d_in[3];
    const float* pose  = (const float*)d_in[4];
    const float* Wq  = (const float*)d_in[5];  const float* bq   = (const float*)d_in[6];
    const float* Wk  = (const float*)d_in[7];  const float* bk   = (const float*)d_in[8];
    const float* Wv  = (const float*)d_in[9];  const float* bv   = (const float*)d_in[10];
    const float* Wo1 = (const float*)d_in[11]; const float* bo1  = (const float*)d_in[12];
    const float* Wo2 = (const float*)d_in[13]; const float* bo2  = (const float*)d_in[14];
    const float* Wpos= (const float*)d_in[15]; const float* bpos = (const float*)d_in[16];
    const float* Wout= (const float*)d_in[17]; const float* bout = (const float*)d_in[18];

    __bf16* ws = (__bf16*)d_ws;

    prep_all<<<2176, 256, 0, stream>>>(Wq, Wk, Wpos, Wo1, Wo2, Wv, Wout, ws);

    fused_ext_attn<<<65536 / MT, 512, 0, stream>>>(
        query, key, value, refp, pose, ws,
        bq, bk, bv, bpos, bo1, bo2, bout, (float*)d_out);
}